// Round 3
// baseline (1000.478 us; speedup 1.0000x reference)
//
#include <hip/hip_runtime.h>

// GATGuard: 2-layer GAT with cosine-similarity edge gating (att_coef).
// N=50000 nodes, E=800000 raw edges, H=4 heads, F=64 feat/head, HF=256.
// Outputs: h1 [N,256], att_w [E], self_w [N]  (concatenated in d_out).

#define NH 4
#define NF 64
#define HF 256

__device__ __forceinline__ float wred_sum(float v) {
#pragma unroll
  for (int o = 32; o > 0; o >>= 1) v += __shfl_xor(v, o, 64);
  return v;
}
__device__ __forceinline__ float lrelu(float x, float s) {
  return x > 0.f ? x : s * x;
}
__device__ __forceinline__ float bf2f(unsigned short u) {
  union { float f; unsigned int i; } v;
  v.i = ((unsigned int)u) << 16;
  return v.f;
}
__device__ __forceinline__ unsigned short f2bf(float f) {  // RNE
  union { float f; unsigned int i; } v;
  v.f = f;
  unsigned int r = v.i + 0x7fffu + ((v.i >> 16) & 1u);
  return (unsigned short)(r >> 16);
}

// ---------------- row inverse L2 norms (wave per row) ----------------
__global__ __launch_bounds__(256) void rownorm_kernel(
    const float* __restrict__ X, float* __restrict__ inv, int n, int D) {
  int row = blockIdx.x * 4 + (threadIdx.x >> 6);
  int lane = threadIdx.x & 63;
  if (row >= n) return;
  const float* p = X + (size_t)row * D;
  float acc = 0.f;
  for (int i = lane; i < D; i += 64) { float v = p[i]; acc += v * v; }
  acc = wred_sum(acc);
  if (lane == 0) inv[row] = 1.f / fmaxf(sqrtf(acc), 1e-12f);
}

// ---------------- normalized bf16 copy of x (for the mask dot) -----------
__global__ __launch_bounds__(256) void xnorm_bf16_kernel(
    const float* __restrict__ X, const float* __restrict__ inv,
    unsigned short* __restrict__ xnb, int n) {
  int idx = blockIdx.x * blockDim.x + threadIdx.x;  // one float2 per thread
  if (idx >= n * 64) return;
  int row = idx >> 6;
  float s = inv[row];
  float2 v = ((const float2*)X)[idx];
  unsigned int packed =
      (unsigned int)f2bf(v.x * s) | ((unsigned int)f2bf(v.y * s) << 16);
  ((unsigned int*)xnb)[idx] = packed;
}

// ---- layer-0 cosine mask, src-CSR (wave per src node) --------------------
// bf16 dot (256 B gather/edge) with exact-f32 fallback near the threshold.
__global__ __launch_bounds__(256) void edge_mask_csr_kernel(
    const unsigned short* __restrict__ xnb, const float* __restrict__ X,
    const float* __restrict__ xinv, const int* __restrict__ rs2,
    const int* __restrict__ c2dst, const int* __restrict__ c2eid,
    unsigned char* __restrict__ mask, int n) {
  int node = blockIdx.x * 4 + (threadIdx.x >> 6);
  int lane = threadIdx.x & 63;
  if (node >= n) return;
  int start = rs2[node], end = rs2[node + 1];
  if (start == end) return;
  // src row, bf16x2 per lane (128 bf16 = 256 B)
  unsigned int sa = ((const unsigned int*)(xnb + (size_t)node * 128))[lane];
  float ax = bf2f((unsigned short)(sa & 0xffff));
  float ay = bf2f((unsigned short)(sa >> 16));
  for (int p = start; p < end; ++p) {
    int d = c2dst[p];
    unsigned int sb = ((const unsigned int*)(xnb + (size_t)d * 128))[lane];
    float acc = ax * bf2f((unsigned short)(sb & 0xffff)) +
                ay * bf2f((unsigned short)(sb >> 16));
    acc = wred_sum(acc);  // broadcast to all lanes
    bool mk;
    if (fabsf(acc - 0.1f) < 4e-3f) {  // exact recheck (~2% of edges)
      const float2* pxs = (const float2*)(X + (size_t)node * 128);
      const float2* pxd = (const float2*)(X + (size_t)d * 128);
      float2 fa = pxs[lane], fb = pxd[lane];
      float a2 = fa.x * fb.x + fa.y * fb.y;
      a2 = wred_sum(a2);
      mk = (a2 * xinv[node] * xinv[d]) >= 0.1f;
    } else {
      mk = acc >= 0.1f;
    }
    if (lane == 0) mask[c2eid[p]] = mk ? 1 : 0;
  }
}

// ---- att_coef #2, src-CSR, fused att_w/self_w (wave per src node) -------
__global__ __launch_bounds__(256) void edge_sim2_csr_kernel(
    const float* __restrict__ Hf, const float* __restrict__ hinv,
    const int* __restrict__ rs2, const int* __restrict__ c2dst,
    const int* __restrict__ c2eid, const unsigned char* __restrict__ mask,
    float* __restrict__ spill, float* __restrict__ out_att,
    float* __restrict__ out_self, int n) {
  int node = blockIdx.x * 4 + (threadIdx.x >> 6);
  int lane = threadIdx.x & 63;
  if (node >= n) return;
  int start = rs2[node], deg = rs2[node + 1] - start;
  float inv_s = hinv[node];
  const float4* hs = (const float4*)(Hf + (size_t)node * 256);
  float4 a = hs[lane];  // 1 KB src row in regs
  float rowsum = 0.f;
  int cnt = 0;
  float svreg = 0.f;  // lane j holds sv of out-edge j (j<64)
  for (int j = 0; j < deg; ++j) {
    int p = start + j;
    int eid = c2eid[p];
    if (!mask[eid]) continue;
    int d = c2dst[p];
    const float4* hd = (const float4*)(Hf + (size_t)d * 256);
    float4 b = hd[lane];
    float acc = a.x * b.x + a.y * b.y + a.z * b.z + a.w * b.w;
    acc = wred_sum(acc);
    float sim = acc * inv_s * hinv[d];
    float sv = (sim >= 0.1f) ? sim : 0.f;
    rowsum += sv;
    cnt += (sv > 0.f) ? 1 : 0;
    if (j < 64) {
      if (lane == j) svreg = sv;
    } else if (lane == 0) {
      spill[eid] = sv;  // Poisson(16) out-degree: essentially never taken
    }
  }
  // pass 2: att_w for ALL out-edges of this node
  for (int i = lane; i < deg; i += 64) {
    int p = start + i;
    int eid = c2eid[p];
    float att = 0.f;
    if (mask[eid]) {
      float sv = (i < 64) ? svreg : spill[eid];
      att = (sv > 0.f) ? __expf(sv / rowsum) : 0.f;
    }
    out_att[eid] = att;
  }
  if (lane == 0) out_self[node] = __expf(1.f / ((float)cnt + 1.f));
}

// ---------------- tiled FP32 GEMM: C[n,M] = A[n,K] @ B[K,M] ----------------
// 128x128 tile, 256 threads, 8x8 microtile, K-tile 16.
__global__ __launch_bounds__(256) void gemm_kernel(
    const float* __restrict__ A, const float* __restrict__ B,
    float* __restrict__ C, int n, int K, int M) {
  __shared__ float As[16][128];
  __shared__ float Bs[16][128];
  int tid = threadIdx.x;
  int tx = tid & 15, ty = tid >> 4;
  int row0 = blockIdx.x * 128;
  int col0 = blockIdx.y * 128;
  float acc[8][8] = {};
  for (int k0 = 0; k0 < K; k0 += 16) {
#pragma unroll
    for (int i = 0; i < 2; ++i) {
      int p = tid + i * 256;
      int r = p >> 2, c4 = p & 3;
      int gr = row0 + r;
      float4 v = make_float4(0.f, 0.f, 0.f, 0.f);
      if (gr < n) v = *(const float4*)(A + (size_t)gr * K + k0 + c4 * 4);
      As[c4 * 4 + 0][r] = v.x;
      As[c4 * 4 + 1][r] = v.y;
      As[c4 * 4 + 2][r] = v.z;
      As[c4 * 4 + 3][r] = v.w;
    }
#pragma unroll
    for (int i = 0; i < 2; ++i) {
      int p = tid + i * 256;
      int r = p >> 5, c4 = p & 31;
      *(float4*)&Bs[r][c4 * 4] =
          *(const float4*)(B + (size_t)(k0 + r) * M + col0 + c4 * 4);
    }
    __syncthreads();
#pragma unroll
    for (int k = 0; k < 16; ++k) {
      float4 a0v = *(const float4*)&As[k][ty * 4];
      float4 a1v = *(const float4*)&As[k][64 + ty * 4];
      float4 b0v = *(const float4*)&Bs[k][tx * 4];
      float4 b1v = *(const float4*)&Bs[k][64 + tx * 4];
      float av[8] = {a0v.x, a0v.y, a0v.z, a0v.w, a1v.x, a1v.y, a1v.z, a1v.w};
      float bv[8] = {b0v.x, b0v.y, b0v.z, b0v.w, b1v.x, b1v.y, b1v.z, b1v.w};
#pragma unroll
      for (int i = 0; i < 8; ++i)
#pragma unroll
        for (int j = 0; j < 8; ++j) acc[i][j] += av[i] * bv[j];
    }
    __syncthreads();
  }
#pragma unroll
  for (int half = 0; half < 2; ++half) {
#pragma unroll
    for (int i = 0; i < 4; ++i) {
      int gr = row0 + half * 64 + ty * 4 + i;
      if (gr < n) {
        float* cp = C + (size_t)gr * M + col0;
        int ai = half * 4 + i;
        *(float4*)(cp + tx * 4) =
            make_float4(acc[ai][0], acc[ai][1], acc[ai][2], acc[ai][3]);
        *(float4*)(cp + 64 + tx * 4) =
            make_float4(acc[ai][4], acc[ai][5], acc[ai][6], acc[ai][7]);
      }
    }
  }
}

// ---------------- el/er per (node, head) ----------------
__global__ __launch_bounds__(256) void elr_kernel(
    const float* __restrict__ feat, const float* __restrict__ a,
    float* __restrict__ el, float* __restrict__ er, int n) {
  int node = blockIdx.x;
  int lane = threadIdx.x & 63;
  int wv = threadIdx.x >> 6;
  if (node >= n) return;
  float f = feat[(size_t)node * HF + wv * NF + lane];
  float p0 = f * a[wv * NF + lane];          // a[0,h,f]
  float p1 = f * a[HF + wv * NF + lane];     // a[1,h,f]
  p0 = wred_sum(p0);
  p1 = wred_sum(p1);
  if (lane == 0) {
    el[node * NH + wv] = p0;
    er[node * NH + wv] = p1;
  }
}

// ---------------- CSR build ----------------
__global__ __launch_bounds__(256) void hist_kernel(
    const int* __restrict__ key, int* __restrict__ deg, int E_) {
  int e = blockIdx.x * blockDim.x + threadIdx.x;
  if (e >= E_) return;
  atomicAdd(&deg[key[e]], 1);
}

// 3-phase scan: per-block scan -> scan of block sums -> add offsets.
__global__ __launch_bounds__(1024) void scanA_kernel(
    const int* __restrict__ deg, int* __restrict__ rs, int* __restrict__ bsum,
    int n) {
  __shared__ int temp[1024];
  int tid = threadIdx.x;
  int idx = blockIdx.x * 1024 + tid;
  int v = (idx < n) ? deg[idx] : 0;
  temp[tid] = v;
  __syncthreads();
  for (int off = 1; off < 1024; off <<= 1) {
    int t = (tid >= off) ? temp[tid - off] : 0;
    __syncthreads();
    temp[tid] += t;
    __syncthreads();
  }
  if (idx < n) rs[idx] = temp[tid] - v;  // block-local exclusive
  if (tid == 1023) bsum[blockIdx.x] = temp[1023];
}

__global__ void scanB_kernel(int* __restrict__ bsum, int nb) {
  if (threadIdx.x == 0) {
    int run = 0;
    for (int i = 0; i < nb; ++i) {
      int v = bsum[i];
      bsum[i] = run;
      run += v;
    }
    bsum[nb] = run;
  }
}

__global__ __launch_bounds__(256) void scanC_kernel(
    int* __restrict__ rs, const int* __restrict__ bsum, int n, int nb) {
  int idx = blockIdx.x * blockDim.x + threadIdx.x;
  if (idx < n) rs[idx] += bsum[idx >> 10];
  else if (idx == n) rs[n] = bsum[nb];
}

// dst-CSR: store src only (for gat_agg)
__global__ __launch_bounds__(256) void scatter_kernel(
    const int* __restrict__ src, const int* __restrict__ dst,
    const int* __restrict__ rs, int* __restrict__ cursor,
    int* __restrict__ csr_src, int E_) {
  int e = blockIdx.x * blockDim.x + threadIdx.x;
  if (e >= E_) return;
  int d = dst[e];
  int pos = rs[d] + atomicAdd(&cursor[d], 1);
  csr_src[pos] = src[e];
}

// src-CSR: store dst + original edge id (for the att_coef passes)
__global__ __launch_bounds__(256) void scatter2_kernel(
    const int* __restrict__ src, const int* __restrict__ dst,
    const int* __restrict__ rs2, int* __restrict__ cursor2,
    int* __restrict__ c2dst, int* __restrict__ c2eid, int E_) {
  int e = blockIdx.x * blockDim.x + threadIdx.x;
  if (e >= E_) return;
  int s = src[e];
  int pos = rs2[s] + atomicAdd(&cursor2[s], 1);
  c2dst[pos] = dst[e];
  c2eid[pos] = e;
}

// ---------------- GAT aggregation (wave per node, float4 per lane) -------
// No segment-max: scores are O(1), exp(e)/sum(exp(e)) is safe (diff ~1e-6).
__global__ __launch_bounds__(256) void gat_agg_kernel(
    const float* __restrict__ feat, const float* __restrict__ el,
    const float* __restrict__ er, const int* __restrict__ row_start,
    const int* __restrict__ csr_src, const float* __restrict__ bias,
    float* __restrict__ out, float* __restrict__ inv_out, int n, int act) {
  int node = blockIdx.x * 4 + (threadIdx.x >> 6);
  int lane = threadIdx.x & 63;
  if (node >= n) return;
  int h = lane >> 4;
  const float4* feat4 = (const float4*)feat;
  float er_n = er[node * NH + h];
  float es = lrelu(el[node * NH + h] + er_n, 0.2f);
  int start = row_start[node];
  int deg = row_start[node + 1] - start;
  float ws = __expf(es);
  float4 fv = feat4[(size_t)node * 64 + lane];
  float4 facc = make_float4(ws * fv.x, ws * fv.y, ws * fv.z, ws * fv.w);
  float z = ws;
#pragma unroll 4
  for (int j = 0; j < deg; ++j) {
    int s = csr_src[start + j];
    float w = __expf(lrelu(el[s * NH + h] + er_n, 0.2f));
    float4 f = feat4[(size_t)s * 64 + lane];
    facc.x += w * f.x;
    facc.y += w * f.y;
    facc.z += w * f.z;
    facc.w += w * f.w;
    z += w;
  }
  float rz = 1.f / z;
  float4 bb = ((const float4*)bias)[lane];
  float4 o_;
  o_.x = facc.x * rz + bb.x;
  o_.y = facc.y * rz + bb.y;
  o_.z = facc.z * rz + bb.z;
  o_.w = facc.w * rz + bb.w;
  if (act) {
    o_.x = lrelu(o_.x, 0.01f);
    o_.y = lrelu(o_.y, 0.01f);
    o_.z = lrelu(o_.z, 0.01f);
    o_.w = lrelu(o_.w, 0.01f);
  }
  ((float4*)out)[(size_t)node * 64 + lane] = o_;
  if (inv_out) {  // fused row-norm for the next att_coef
    float sq = o_.x * o_.x + o_.y * o_.y + o_.z * o_.z + o_.w * o_.w;
    sq = wred_sum(sq);
    if (lane == 0) inv_out[node] = 1.f / fmaxf(sqrtf(sq), 1e-12f);
  }
}

extern "C" void kernel_launch(void* const* d_in, const int* in_sizes, int n_in,
                              void* d_out, int out_size, void* d_ws, size_t ws_size,
                              hipStream_t stream) {
  const float* x = (const float*)d_in[0];
  const int* esrc = (const int*)d_in[1];
  const int* edst = (const int*)d_in[2];
  const float* W0 = (const float*)d_in[3];
  const float* a0 = (const float*)d_in[4];
  const float* b0 = (const float*)d_in[5];
  const float* W1 = (const float*)d_in[6];
  const float* a1 = (const float*)d_in[7];
  const float* b1 = (const float*)d_in[8];

  const int N = in_sizes[0] / 128;  // 50000
  const int E = in_sizes[1];        // 800000

  // ---- workspace layout (256B aligned chunks) ----
  char* wp = (char*)d_ws;
  auto alloc = [&](size_t bytes) {
    char* p = wp;
    wp += (bytes + 255) & ~(size_t)255;
    return p;
  };
  float* h0 = (float*)alloc((size_t)N * HF * 4);
  float* featb = (float*)alloc((size_t)N * HF * 4);
  float* xinv = (float*)alloc((size_t)N * 4);
  float* h0inv = (float*)alloc((size_t)N * 4);
  float* el = (float*)alloc((size_t)N * NH * 4);
  float* er = (float*)alloc((size_t)N * NH * 4);
  unsigned char* mask1 = (unsigned char*)alloc((size_t)E);
  float* spill = (float*)alloc((size_t)E * 4);
  unsigned short* xnb = (unsigned short*)alloc((size_t)N * 128 * 2);
  int* deg_i = (int*)alloc((size_t)N * 4);
  int* row_start = (int*)alloc((size_t)(N + 1) * 4);
  int* cursor = (int*)alloc((size_t)N * 4);
  int* csr_src = (int*)alloc((size_t)E * 4);
  int* deg2_i = (int*)alloc((size_t)N * 4);
  int* row_start2 = (int*)alloc((size_t)(N + 1) * 4);
  int* cursor2 = (int*)alloc((size_t)N * 4);
  int* c2dst = (int*)alloc((size_t)E * 4);
  int* c2eid = (int*)alloc((size_t)E * 4);
  const int NSB = (N + 1023) / 1024;  // scan blocks
  int* bsum = (int*)alloc((size_t)(NSB + 1) * 4);
  int* bsum2 = (int*)alloc((size_t)(NSB + 1) * 4);

  float* out_h = (float*)d_out;            // [N,256]
  float* out_att = out_h + (size_t)N * HF; // [E]
  float* out_self = out_att + E;           // [N]

  const int NB4 = (N + 3) / 4;        // wave-per-node grids
  const int EBT = (E + 255) / 256;    // thread-per-edge grids

  // ---- zero accumulators (ws is poisoned before every call) ----
  hipMemsetAsync(deg_i, 0, (size_t)N * 4, stream);
  hipMemsetAsync(cursor, 0, (size_t)N * 4, stream);
  hipMemsetAsync(deg2_i, 0, (size_t)N * 4, stream);
  hipMemsetAsync(cursor2, 0, (size_t)N * 4, stream);

  // ---- CSR by dst (gat_agg) and by src (att_coef) ----
  hist_kernel<<<EBT, 256, 0, stream>>>(edst, deg_i, E);
  hist_kernel<<<EBT, 256, 0, stream>>>(esrc, deg2_i, E);
  scanA_kernel<<<NSB, 1024, 0, stream>>>(deg_i, row_start, bsum, N);
  scanB_kernel<<<1, 64, 0, stream>>>(bsum, NSB);
  scanC_kernel<<<(N + 256) / 256, 256, 0, stream>>>(row_start, bsum, N, NSB);
  scanA_kernel<<<NSB, 1024, 0, stream>>>(deg2_i, row_start2, bsum2, N);
  scanB_kernel<<<1, 64, 0, stream>>>(bsum2, NSB);
  scanC_kernel<<<(N + 256) / 256, 256, 0, stream>>>(row_start2, bsum2, N, NSB);
  scatter_kernel<<<EBT, 256, 0, stream>>>(esrc, edst, row_start, cursor,
                                          csr_src, E);
  scatter2_kernel<<<EBT, 256, 0, stream>>>(esrc, edst, row_start2, cursor2,
                                           c2dst, c2eid, E);

  // ---- att_coef #1 on x: only the mask survives ----
  rownorm_kernel<<<NB4, 256, 0, stream>>>(x, xinv, N, 128);
  xnorm_bf16_kernel<<<(N * 64 + 255) / 256, 256, 0, stream>>>(x, xinv, xnb, N);
  edge_mask_csr_kernel<<<NB4, 256, 0, stream>>>(xnb, x, xinv, row_start2,
                                                c2dst, c2eid, mask1, N);

  // ---- layer 0: feat = x@W0; el/er; aggregate -> h0 (leaky_relu 0.01) ----
  {
    dim3 g((N + 127) / 128, HF / 128);
    gemm_kernel<<<g, 256, 0, stream>>>(x, W0, featb, N, 128, HF);
  }
  elr_kernel<<<N, 256, 0, stream>>>(featb, a0, el, er, N);
  gat_agg_kernel<<<NB4, 256, 0, stream>>>(featb, el, er, row_start, csr_src,
                                          b0, h0, h0inv, N, 1);

  // ---- att_coef #2 on h0: fused att_w + self_w ----
  edge_sim2_csr_kernel<<<NB4, 256, 0, stream>>>(h0, h0inv, row_start2, c2dst,
                                                c2eid, mask1, spill, out_att,
                                                out_self, N);

  // ---- layer 1: feat = h0@W1; el/er; aggregate -> out_h (no act) ----
  {
    dim3 g((N + 127) / 128, HF / 128);
    gemm_kernel<<<g, 256, 0, stream>>>(h0, W1, featb, N, 256, HF);
  }
  elr_kernel<<<N, 256, 0, stream>>>(featb, a1, el, er, N);
  gat_agg_kernel<<<NB4, 256, 0, stream>>>(featb, el, er, row_start, csr_src,
                                          b1, out_h, nullptr, N, 0);
}

// Round 4
// 836.804 us; speedup vs baseline: 1.1956x; 1.1956x over previous
//
#include <hip/hip_runtime.h>

// GATGuard: 2-layer GAT with cosine-similarity edge gating (att_coef).
// N=50000 nodes, E=800000 raw edges, H=4 heads, F=64 feat/head, HF=256.
// Outputs: h1 [N,256], att_w [E], self_w [N]  (concatenated in d_out).

#define NH 4
#define NF 64
#define HF 256

__device__ __forceinline__ float wred_sum(float v) {
#pragma unroll
  for (int o = 32; o > 0; o >>= 1) v += __shfl_xor(v, o, 64);
  return v;
}
__device__ __forceinline__ float lrelu(float x, float s) {
  return x > 0.f ? x : s * x;
}
__device__ __forceinline__ float bf2f(unsigned short u) {
  union { float f; unsigned int i; } v;
  v.i = ((unsigned int)u) << 16;
  return v.f;
}
__device__ __forceinline__ unsigned short f2bf(float f) {  // RNE
  union { float f; unsigned int i; } v;
  v.f = f;
  unsigned int r = v.i + 0x7fffu + ((v.i >> 16) & 1u);
  return (unsigned short)(r >> 16);
}
__device__ __forceinline__ float dot_bf16x8(uint4 a, uint4 b) {
  const unsigned int* pa = (const unsigned int*)&a;
  const unsigned int* pb = (const unsigned int*)&b;
  float acc = 0.f;
#pragma unroll
  for (int i = 0; i < 4; ++i) {
    acc += bf2f((unsigned short)(pa[i] & 0xffff)) *
           bf2f((unsigned short)(pb[i] & 0xffff));
    acc += bf2f((unsigned short)(pa[i] >> 16)) *
           bf2f((unsigned short)(pb[i] >> 16));
  }
  return acc;
}

// ---- fused row-norm + normalized bf16 copy of x (wave per row, D=128) ----
__global__ __launch_bounds__(256) void xprep_kernel(
    const float* __restrict__ X, float* __restrict__ inv,
    unsigned short* __restrict__ xnb, int n) {
  int row = blockIdx.x * 4 + (threadIdx.x >> 6);
  int lane = threadIdx.x & 63;
  if (row >= n) return;
  float2 v = ((const float2*)(X + (size_t)row * 128))[lane];
  float acc = v.x * v.x + v.y * v.y;
  acc = wred_sum(acc);
  float s = 1.f / fmaxf(sqrtf(acc), 1e-12f);
  if (lane == 0) inv[row] = s;
  unsigned int packed =
      (unsigned int)f2bf(v.x * s) | ((unsigned int)f2bf(v.y * s) << 16);
  ((unsigned int*)(xnb + (size_t)row * 128))[lane] = packed;
}

// ---- layer-0 cosine mask: 8-lane group per edge, CSR-by-src order --------
// bf16 dot (256 B dst gather; src row L1-hot) + exact f32 recheck near 0.1.
__global__ __launch_bounds__(256) void edge_mask8_kernel(
    const unsigned short* __restrict__ xnb, const float* __restrict__ X,
    const float* __restrict__ xinv, const int* __restrict__ c2src,
    const int* __restrict__ c2dst, int* __restrict__ mask2, int E_) {
  int p = blockIdx.x * 32 + (threadIdx.x >> 3);
  int gl = threadIdx.x & 7;
  if (p >= E_) return;
  int s = c2src[p], d = c2dst[p];
  const uint4* ps = (const uint4*)(xnb + (size_t)s * 128);
  const uint4* pd = (const uint4*)(xnb + (size_t)d * 128);
  uint4 a0 = ps[gl], a1 = ps[gl + 8];
  uint4 b0 = pd[gl], b1 = pd[gl + 8];
  float acc = dot_bf16x8(a0, b0) + dot_bf16x8(a1, b1);
#pragma unroll
  for (int o = 1; o < 8; o <<= 1) acc += __shfl_xor(acc, o, 64);
  bool mk;
  if (fabsf(acc - 0.1f) < 4e-3f) {  // exact recheck (~2% of edges)
    const float4* fs = (const float4*)(X + (size_t)s * 128);
    const float4* fd = (const float4*)(X + (size_t)d * 128);
    float a2 = 0.f;
#pragma unroll
    for (int i = 0; i < 4; ++i) {
      float4 fa = fs[gl + 8 * i], fb = fd[gl + 8 * i];
      a2 += fa.x * fb.x + fa.y * fb.y + fa.z * fb.z + fa.w * fb.w;
    }
#pragma unroll
    for (int o = 1; o < 8; o <<= 1) a2 += __shfl_xor(a2, o, 64);
    mk = (a2 * xinv[s] * xinv[d]) >= 0.1f;
  } else {
    mk = acc >= 0.1f;
  }
  if (gl == 0) mask2[p] = mk ? 1 : 0;
}

// ---- compact surviving edges (deterministic via prefix scan) ------------
__global__ __launch_bounds__(256) void compact_kernel(
    const int* __restrict__ mask2, const int* __restrict__ pos2,
    const int* __restrict__ c2src, const int* __restrict__ c2dst,
    const int* __restrict__ c2eid, int* __restrict__ cs, int* __restrict__ cd,
    int* __restrict__ ce, int E_) {
  int p = blockIdx.x * blockDim.x + threadIdx.x;
  if (p >= E_) return;
  if (mask2[p]) {
    int q = pos2[p];
    cs[q] = c2src[p];
    cd[q] = c2dst[p];
    ce[q] = c2eid[p];
  }
}

// ---- att_coef #2 over compacted survivors: 16-lane group per edge -------
__global__ __launch_bounds__(256) void sim2_kernel(
    const float* __restrict__ Hf, const float* __restrict__ hinv,
    const int* __restrict__ cs, const int* __restrict__ cd,
    const int* __restrict__ total, float* __restrict__ svc,
    float* __restrict__ rowsum, float* __restrict__ degf) {
  int S = total[0];
  int gl = threadIdx.x & 15;
  int g0 = blockIdx.x * 16 + (threadIdx.x >> 4);
  int gstride = gridDim.x * 16;
  for (int q = g0; q < S; q += gstride) {
    int s = cs[q], d = cd[q];
    const float4* hs = (const float4*)(Hf + (size_t)s * 256);
    const float4* hd = (const float4*)(Hf + (size_t)d * 256);
    float acc = 0.f;
#pragma unroll
    for (int i = 0; i < 4; ++i) {
      float4 a = hs[gl + 16 * i], b = hd[gl + 16 * i];
      acc += a.x * b.x + a.y * b.y + a.z * b.z + a.w * b.w;
    }
#pragma unroll
    for (int o = 1; o < 16; o <<= 1) acc += __shfl_xor(acc, o, 64);
    if (gl == 0) {
      float sim = acc * hinv[s] * hinv[d];
      float sv = (sim >= 0.1f) ? sim : 0.f;
      svc[q] = sv;
      if (sv > 0.f) {
        atomicAdd(&rowsum[s], sv);
        atomicAdd(&degf[s], 1.0f);
      }
    }
  }
}

// ---- att_w over survivors (out_att pre-zeroed) ---------------------------
__global__ __launch_bounds__(256) void att_w_kernel(
    const float* __restrict__ svc, const float* __restrict__ rowsum,
    const int* __restrict__ cs, const int* __restrict__ ce,
    const int* __restrict__ total, float* __restrict__ out_att) {
  int S = total[0];
  int stride = gridDim.x * blockDim.x;
  for (int q = blockIdx.x * blockDim.x + threadIdx.x; q < S; q += stride) {
    float sv = svc[q];
    if (sv > 0.f) out_att[ce[q]] = __expf(sv / rowsum[cs[q]]);
  }
}

// ---- self_w (thread per node) --------------------------------------------
__global__ __launch_bounds__(256) void self_w_kernel(
    const float* __restrict__ degf, float* __restrict__ out_self, int n) {
  int i = blockIdx.x * blockDim.x + threadIdx.x;
  if (i >= n) return;
  out_self[i] = __expf(1.f / (degf[i] + 1.f));
}

// ---------------- tiled FP32 GEMM: C[n,M] = A[n,K] @ B[K,M] ----------------
// 128x128 tile, 256 threads, 8x8 microtile, K-tile 16.
__global__ __launch_bounds__(256) void gemm_kernel(
    const float* __restrict__ A, const float* __restrict__ B,
    float* __restrict__ C, int n, int K, int M) {
  __shared__ float As[16][128];
  __shared__ float Bs[16][128];
  int tid = threadIdx.x;
  int tx = tid & 15, ty = tid >> 4;
  int row0 = blockIdx.x * 128;
  int col0 = blockIdx.y * 128;
  float acc[8][8] = {};
  for (int k0 = 0; k0 < K; k0 += 16) {
#pragma unroll
    for (int i = 0; i < 2; ++i) {
      int p = tid + i * 256;
      int r = p >> 2, c4 = p & 3;
      int gr = row0 + r;
      float4 v = make_float4(0.f, 0.f, 0.f, 0.f);
      if (gr < n) v = *(const float4*)(A + (size_t)gr * K + k0 + c4 * 4);
      As[c4 * 4 + 0][r] = v.x;
      As[c4 * 4 + 1][r] = v.y;
      As[c4 * 4 + 2][r] = v.z;
      As[c4 * 4 + 3][r] = v.w;
    }
#pragma unroll
    for (int i = 0; i < 2; ++i) {
      int p = tid + i * 256;
      int r = p >> 5, c4 = p & 31;
      *(float4*)&Bs[r][c4 * 4] =
          *(const float4*)(B + (size_t)(k0 + r) * M + col0 + c4 * 4);
    }
    __syncthreads();
#pragma unroll
    for (int k = 0; k < 16; ++k) {
      float4 a0v = *(const float4*)&As[k][ty * 4];
      float4 a1v = *(const float4*)&As[k][64 + ty * 4];
      float4 b0v = *(const float4*)&Bs[k][tx * 4];
      float4 b1v = *(const float4*)&Bs[k][64 + tx * 4];
      float av[8] = {a0v.x, a0v.y, a0v.z, a0v.w, a1v.x, a1v.y, a1v.z, a1v.w};
      float bv[8] = {b0v.x, b0v.y, b0v.z, b0v.w, b1v.x, b1v.y, b1v.z, b1v.w};
#pragma unroll
      for (int i = 0; i < 8; ++i)
#pragma unroll
        for (int j = 0; j < 8; ++j) acc[i][j] += av[i] * bv[j];
    }
    __syncthreads();
  }
#pragma unroll
  for (int half = 0; half < 2; ++half) {
#pragma unroll
    for (int i = 0; i < 4; ++i) {
      int gr = row0 + half * 64 + ty * 4 + i;
      if (gr < n) {
        float* cp = C + (size_t)gr * M + col0;
        int ai = half * 4 + i;
        *(float4*)(cp + tx * 4) =
            make_float4(acc[ai][0], acc[ai][1], acc[ai][2], acc[ai][3]);
        *(float4*)(cp + 64 + tx * 4) =
            make_float4(acc[ai][4], acc[ai][5], acc[ai][6], acc[ai][7]);
      }
    }
  }
}

// ---------------- el/er per (node, head) ----------------
__global__ __launch_bounds__(256) void elr_kernel(
    const float* __restrict__ feat, const float* __restrict__ a,
    float* __restrict__ el, float* __restrict__ er, int n) {
  int node = blockIdx.x;
  int lane = threadIdx.x & 63;
  int wv = threadIdx.x >> 6;
  if (node >= n) return;
  float f = feat[(size_t)node * HF + wv * NF + lane];
  float p0 = f * a[wv * NF + lane];          // a[0,h,f]
  float p1 = f * a[HF + wv * NF + lane];     // a[1,h,f]
  p0 = wred_sum(p0);
  p1 = wred_sum(p1);
  if (lane == 0) {
    el[node * NH + wv] = p0;
    er[node * NH + wv] = p1;
  }
}

// ---------------- CSR build ----------------
__global__ __launch_bounds__(256) void hist_kernel(
    const int* __restrict__ key, int* __restrict__ deg, int E_) {
  int e = blockIdx.x * blockDim.x + threadIdx.x;
  if (e >= E_) return;
  atomicAdd(&deg[key[e]], 1);
}

// 3-phase scan: per-block scan -> parallel scan of block sums -> add offsets.
__global__ __launch_bounds__(1024) void scanA_kernel(
    const int* __restrict__ deg, int* __restrict__ rs, int* __restrict__ bsum,
    int n) {
  __shared__ int temp[1024];
  int tid = threadIdx.x;
  int idx = blockIdx.x * 1024 + tid;
  int v = (idx < n) ? deg[idx] : 0;
  temp[tid] = v;
  __syncthreads();
  for (int off = 1; off < 1024; off <<= 1) {
    int t = (tid >= off) ? temp[tid - off] : 0;
    __syncthreads();
    temp[tid] += t;
    __syncthreads();
  }
  if (idx < n) rs[idx] = temp[tid] - v;  // block-local exclusive
  if (tid == 1023) bsum[blockIdx.x] = temp[1023];
}

// parallel block-sum scan (nb <= 1024)
__global__ __launch_bounds__(1024) void scanB_kernel(int* __restrict__ bsum,
                                                     int nb) {
  __shared__ int t[1024];
  int tid = threadIdx.x;
  int v = (tid < nb) ? bsum[tid] : 0;
  t[tid] = v;
  __syncthreads();
  for (int off = 1; off < 1024; off <<= 1) {
    int u = (tid >= off) ? t[tid - off] : 0;
    __syncthreads();
    t[tid] += u;
    __syncthreads();
  }
  if (tid < nb) bsum[tid] = t[tid] - v;  // exclusive
  if (tid == 0) bsum[nb] = t[1023];      // total
}

__global__ __launch_bounds__(256) void scanC_kernel(
    int* __restrict__ rs, const int* __restrict__ bsum, int n, int nb) {
  int idx = blockIdx.x * blockDim.x + threadIdx.x;
  if (idx < n) rs[idx] += bsum[idx >> 10];
  else if (idx == n) rs[n] = bsum[nb];
}

// dst-CSR: store src only (for gat_agg)
__global__ __launch_bounds__(256) void scatter_kernel(
    const int* __restrict__ src, const int* __restrict__ dst,
    const int* __restrict__ rs, int* __restrict__ cursor,
    int* __restrict__ csr_src, int E_) {
  int e = blockIdx.x * blockDim.x + threadIdx.x;
  if (e >= E_) return;
  int d = dst[e];
  int pos = rs[d] + atomicAdd(&cursor[d], 1);
  csr_src[pos] = src[e];
}

// src-CSR: store src, dst, original edge id (for the att_coef passes)
__global__ __launch_bounds__(256) void scatter2_kernel(
    const int* __restrict__ src, const int* __restrict__ dst,
    const int* __restrict__ rs2, int* __restrict__ cursor2,
    int* __restrict__ c2src, int* __restrict__ c2dst,
    int* __restrict__ c2eid, int E_) {
  int e = blockIdx.x * blockDim.x + threadIdx.x;
  if (e >= E_) return;
  int s = src[e];
  int pos = rs2[s] + atomicAdd(&cursor2[s], 1);
  c2src[pos] = s;
  c2dst[pos] = dst[e];
  c2eid[pos] = e;
}

// ---------------- GAT aggregation (wave per node, float4 per lane) -------
// No segment-max: scores are O(1), exp(e)/sum(exp(e)) is safe (diff ~1e-6).
__global__ __launch_bounds__(256) void gat_agg_kernel(
    const float* __restrict__ feat, const float* __restrict__ el,
    const float* __restrict__ er, const int* __restrict__ row_start,
    const int* __restrict__ csr_src, const float* __restrict__ bias,
    float* __restrict__ out, float* __restrict__ inv_out, int n, int act) {
  int node = blockIdx.x * 4 + (threadIdx.x >> 6);
  int lane = threadIdx.x & 63;
  if (node >= n) return;
  int h = lane >> 4;
  const float4* feat4 = (const float4*)feat;
  float er_n = er[node * NH + h];
  float es = lrelu(el[node * NH + h] + er_n, 0.2f);
  int start = row_start[node];
  int deg = row_start[node + 1] - start;
  float ws = __expf(es);
  float4 fv = feat4[(size_t)node * 64 + lane];
  float4 facc = make_float4(ws * fv.x, ws * fv.y, ws * fv.z, ws * fv.w);
  float z = ws;
#pragma unroll 4
  for (int j = 0; j < deg; ++j) {
    int s = csr_src[start + j];
    float w = __expf(lrelu(el[s * NH + h] + er_n, 0.2f));
    float4 f = feat4[(size_t)s * 64 + lane];
    facc.x += w * f.x;
    facc.y += w * f.y;
    facc.z += w * f.z;
    facc.w += w * f.w;
    z += w;
  }
  float rz = 1.f / z;
  float4 bb = ((const float4*)bias)[lane];
  float4 o_;
  o_.x = facc.x * rz + bb.x;
  o_.y = facc.y * rz + bb.y;
  o_.z = facc.z * rz + bb.z;
  o_.w = facc.w * rz + bb.w;
  if (act) {
    o_.x = lrelu(o_.x, 0.01f);
    o_.y = lrelu(o_.y, 0.01f);
    o_.z = lrelu(o_.z, 0.01f);
    o_.w = lrelu(o_.w, 0.01f);
  }
  ((float4*)out)[(size_t)node * 64 + lane] = o_;
  if (inv_out) {  // fused row-norm for the next att_coef
    float sq = o_.x * o_.x + o_.y * o_.y + o_.z * o_.z + o_.w * o_.w;
    sq = wred_sum(sq);
    if (lane == 0) inv_out[node] = 1.f / fmaxf(sqrtf(sq), 1e-12f);
  }
}

extern "C" void kernel_launch(void* const* d_in, const int* in_sizes, int n_in,
                              void* d_out, int out_size, void* d_ws, size_t ws_size,
                              hipStream_t stream) {
  const float* x = (const float*)d_in[0];
  const int* esrc = (const int*)d_in[1];
  const int* edst = (const int*)d_in[2];
  const float* W0 = (const float*)d_in[3];
  const float* a0 = (const float*)d_in[4];
  const float* b0 = (const float*)d_in[5];
  const float* W1 = (const float*)d_in[6];
  const float* a1 = (const float*)d_in[7];
  const float* b1 = (const float*)d_in[8];

  const int N = in_sizes[0] / 128;  // 50000
  const int E = in_sizes[1];        // 800000

  // ---- workspace layout (256B aligned chunks) ----
  char* wp = (char*)d_ws;
  auto alloc = [&](size_t bytes) {
    char* p = wp;
    wp += (bytes + 255) & ~(size_t)255;
    return p;
  };
  float* h0 = (float*)alloc((size_t)N * HF * 4);
  float* featb = (float*)alloc((size_t)N * HF * 4);
  float* xinv = (float*)alloc((size_t)N * 4);
  float* h0inv = (float*)alloc((size_t)N * 4);
  float* el = (float*)alloc((size_t)N * NH * 4);
  float* er = (float*)alloc((size_t)N * NH * 4);
  unsigned short* xnb = (unsigned short*)alloc((size_t)N * 128 * 2);
  int* mask2 = (int*)alloc((size_t)E * 4);
  int* pos2 = (int*)alloc((size_t)(E + 1) * 4);
  float* svc = (float*)alloc((size_t)E * 4);
  float* rowsum = (float*)alloc((size_t)N * 4);
  float* degf = (float*)alloc((size_t)N * 4);
  int* deg_i = (int*)alloc((size_t)N * 4);
  int* row_start = (int*)alloc((size_t)(N + 1) * 4);
  int* cursor = (int*)alloc((size_t)N * 4);
  int* csr_src = (int*)alloc((size_t)E * 4);
  int* deg2_i = (int*)alloc((size_t)N * 4);
  int* row_start2 = (int*)alloc((size_t)(N + 1) * 4);
  int* cursor2 = (int*)alloc((size_t)N * 4);
  int* c2src = (int*)alloc((size_t)E * 4);
  int* c2dst = (int*)alloc((size_t)E * 4);
  int* c2eid = (int*)alloc((size_t)E * 4);
  int* cs = (int*)alloc((size_t)E * 4);
  int* cd = (int*)alloc((size_t)E * 4);
  int* ce = (int*)alloc((size_t)E * 4);
  const int NSB = (N + 1023) / 1024;  // node-scan blocks
  const int ESB = (E + 1023) / 1024;  // edge-scan blocks
  int* bsum = (int*)alloc((size_t)(NSB + 1) * 4);
  int* bsum2 = (int*)alloc((size_t)(NSB + 1) * 4);
  int* bsumE = (int*)alloc((size_t)(ESB + 1) * 4);

  float* out_h = (float*)d_out;            // [N,256]
  float* out_att = out_h + (size_t)N * HF; // [E]
  float* out_self = out_att + E;           // [N]

  const int NB4 = (N + 3) / 4;        // wave-per-node grids
  const int EBT = (E + 255) / 256;    // thread-per-edge grids
  const int NBT = (N + 255) / 256;
  const int EB8 = (E + 31) / 32;      // 8-lane-group-per-edge grid

  // ---- zero accumulators (ws/d_out are poisoned before every call) ----
  hipMemsetAsync(deg_i, 0, (size_t)N * 4, stream);
  hipMemsetAsync(cursor, 0, (size_t)N * 4, stream);
  hipMemsetAsync(deg2_i, 0, (size_t)N * 4, stream);
  hipMemsetAsync(cursor2, 0, (size_t)N * 4, stream);
  hipMemsetAsync(rowsum, 0, (size_t)N * 4, stream);
  hipMemsetAsync(degf, 0, (size_t)N * 4, stream);
  hipMemsetAsync(out_att, 0, (size_t)E * 4, stream);

  // ---- CSR by dst (gat_agg) and by src (att_coef) ----
  hist_kernel<<<EBT, 256, 0, stream>>>(edst, deg_i, E);
  hist_kernel<<<EBT, 256, 0, stream>>>(esrc, deg2_i, E);
  scanA_kernel<<<NSB, 1024, 0, stream>>>(deg_i, row_start, bsum, N);
  scanB_kernel<<<1, 1024, 0, stream>>>(bsum, NSB);
  scanC_kernel<<<(N + 256) / 256, 256, 0, stream>>>(row_start, bsum, N, NSB);
  scanA_kernel<<<NSB, 1024, 0, stream>>>(deg2_i, row_start2, bsum2, N);
  scanB_kernel<<<1, 1024, 0, stream>>>(bsum2, NSB);
  scanC_kernel<<<(N + 256) / 256, 256, 0, stream>>>(row_start2, bsum2, N, NSB);
  scatter_kernel<<<EBT, 256, 0, stream>>>(esrc, edst, row_start, cursor,
                                          csr_src, E);
  scatter2_kernel<<<EBT, 256, 0, stream>>>(esrc, edst, row_start2, cursor2,
                                           c2src, c2dst, c2eid, E);

  // ---- att_coef #1 on x: bf16 cosine mask, edge-parallel ----
  xprep_kernel<<<NB4, 256, 0, stream>>>(x, xinv, xnb, N);
  edge_mask8_kernel<<<EB8, 256, 0, stream>>>(xnb, x, xinv, c2src, c2dst,
                                             mask2, E);
  // compact survivors (deterministic prefix scan)
  scanA_kernel<<<ESB, 1024, 0, stream>>>(mask2, pos2, bsumE, E);
  scanB_kernel<<<1, 1024, 0, stream>>>(bsumE, ESB);
  scanC_kernel<<<(E + 256) / 256, 256, 0, stream>>>(pos2, bsumE, E, ESB);
  compact_kernel<<<EBT, 256, 0, stream>>>(mask2, pos2, c2src, c2dst, c2eid,
                                          cs, cd, ce, E);

  // ---- layer 0: feat = x@W0; el/er; aggregate -> h0 (leaky_relu 0.01) ----
  {
    dim3 g((N + 127) / 128, HF / 128);
    gemm_kernel<<<g, 256, 0, stream>>>(x, W0, featb, N, 128, HF);
  }
  elr_kernel<<<N, 256, 0, stream>>>(featb, a0, el, er, N);
  gat_agg_kernel<<<NB4, 256, 0, stream>>>(featb, el, er, row_start, csr_src,
                                          b0, h0, h0inv, N, 1);

  // ---- att_coef #2 on h0 over survivors: att_w + self_w ----
  sim2_kernel<<<2048, 256, 0, stream>>>(h0, h0inv, cs, cd, pos2 + E, svc,
                                        rowsum, degf);
  att_w_kernel<<<1024, 256, 0, stream>>>(svc, rowsum, cs, ce, pos2 + E,
                                         out_att);
  self_w_kernel<<<NBT, 256, 0, stream>>>(degf, out_self, N);

  // ---- layer 1: feat = h0@W1; el/er; aggregate -> out_h (no act) ----
  {
    dim3 g((N + 127) / 128, HF / 128);
    gemm_kernel<<<g, 256, 0, stream>>>(h0, W1, featb, N, 256, HF);
  }
  elr_kernel<<<N, 256, 0, stream>>>(featb, a1, el, er, N);
  gat_agg_kernel<<<NB4, 256, 0, stream>>>(featb, el, er, row_start, csr_src,
                                          b1, out_h, nullptr, N, 0);
}